// Round 11
// baseline (165.514 us; speedup 1.0000x reference)
//
#include <hip/hip_runtime.h>
#include <math.h>

#define NB 4096
#define HL 50
#define WPB 8   // waves per block; one batch row per wave; 40KB weight pack shared

typedef __attribute__((ext_vector_type(8))) short short8;   // 8 bf16 (4 VGPRs)
typedef __attribute__((ext_vector_type(4))) float f32x4;    // MFMA acc

union frag_u { uint4 q; short8 s; };

// round-to-nearest-even f32->bf16, pack two into u32 (a=low half, b=high half)
__device__ __forceinline__ unsigned pk2(float a, float b) {
    union { float f; unsigned u; } x, y;
    x.f = a; y.f = b;
    unsigned lo = (x.u + 0x7FFFu + ((x.u >> 16) & 1u)) >> 16;
    unsigned hi = (y.u + 0x7FFFu + ((y.u >> 16) & 1u)) & 0xFFFF0000u;
    return lo | hi;
}
__device__ __forceinline__ float ubf_lo(unsigned u) {
    union { unsigned v; float f; } x; x.v = u << 16; return x.f;
}
__device__ __forceinline__ float ubf_hi(unsigned u) {
    union { unsigned v; float f; } x; x.v = u & 0xFFFF0000u; return x.f;
}
__device__ __forceinline__ f32x4 relu4(f32x4 v) {
    f32x4 r;
    r[0] = fmaxf(v[0], 0.f); r[1] = fmaxf(v[1], 0.f);
    r[2] = fmaxf(v[2], 0.f); r[3] = fmaxf(v[3], 0.f);
    return r;
}

// wave = one batch row. MFMA: channels = M, entries = N.
// Weight A-fragments packed once/block (amortized over 8 waves).
// k-slot permutation applied identically on A-pack and B-stage sides -> cancels.
__global__ __launch_bounds__(512, 4) void uvagg(
    const int* __restrict__ nodes,
    const int* __restrict__ history_uv,
    const int* __restrict__ history_r,
    const int* __restrict__ lengths,
    const float* __restrict__ u2e,
    const float* __restrict__ v2e,
    const float* __restrict__ r2e,
    const float* __restrict__ w1,
    const float* __restrict__ b1,
    const float* __restrict__ w2,
    const float* __restrict__ b2,
    const float* __restrict__ a1,
    const float* __restrict__ ba1,
    const float* __restrict__ a2,
    const float* __restrict__ ba2,
    const float* __restrict__ a3,
    const float* __restrict__ ba3,
    float* __restrict__ out)
{
    const int wv   = threadIdx.x >> 6;
    const int lane = threadIdx.x & 63;
    const int g    = lane >> 4;      // k-group / row-group
    const int c16  = lane & 15;      // col-within-tile
    const int b    = blockIdx.x * WPB + wv;

    __shared__ uint4 s_wpack[40 * 64];                 // 40 KB, block-shared
    __shared__ __align__(16) float s_c1[WPB][64];      // 2 KB
    __shared__ uint4 s_stage[WPB][256];                // 32 KB (B-stage / transitions)

    // ---- cooperative weight packing: tiles 0-15 w1^T, 16-23 w2^T, 24-31 a1^T(k<64), 32-39 a2^T ----
    {
        const int tid = threadIdx.x;
        #pragma unroll 1
        for (int t = tid; t < 2560; t += 512) {
            const int tile = t >> 6, ln = t & 63;
            const float* src; int kb, mt;
            if (tile < 16)      { src = w1; kb = (tile & 3) * 32; mt = tile >> 2; }
            else if (tile < 24) { src = w2; kb = (tile & 1) * 32; mt = (tile - 16) >> 1; }
            else if (tile < 32) { src = a1; kb = (tile & 1) * 32; mt = (tile - 24) >> 1; }
            else                { src = a2; kb = (tile & 1) * 32; mt = (tile - 32) >> 1; }
            const float* p = src + (size_t)(kb + (ln >> 4) * 8) * 64 + mt * 16 + (ln & 15);
            uint4 o;
            o.x = pk2(p[0 * 64], p[1 * 64]);
            o.y = pk2(p[2 * 64], p[3 * 64]);
            o.z = pk2(p[4 * 64], p[5 * 64]);
            o.w = pk2(p[6 * 64], p[7 * 64]);
            s_wpack[tile * 64 + ln] = o;
        }
    }

    const int node = nodes[b];     // uniform
    const int len  = lengths[b];   // uniform
    const float uvl = u2e[node * 64 + lane];

    // ---- c1[j] = ba1[j] + sum_k uv[k]*a1[(64+k)*64+j]  (lane = j) ----
    {
        float c1 = ba1[lane];
        #pragma unroll 16
        for (int k = 0; k < 64; ++k)
            c1 = fmaf(__shfl(uvl, k, 64), a1[(64 + k) * 64 + lane], c1);
        s_c1[wv][lane] = c1;
    }
    __syncthreads();   // weights packed + c1 ready

    // ---- gather pointers (lane = entry) ----
    const bool e_ok = (lane < HL);
    const int  hidx = b * HL + (e_ok ? lane : 0);
    const float4* euv4 = (const float4*)(v2e + (size_t)history_uv[hidx] * 64);
    const float4* er4  = (const float4*)(r2e + (size_t)history_r[hidx] * 64);

    uint4* stw = &s_stage[wv][0];
    uint2* t2  = (uint2*)stw;

    // transition write index per mt (C pair {c0,c0+1},{c0+2,c0+3} -> B' slots)
    int twi[4];
    #pragma unroll
    for (int mt = 0; mt < 4; ++mt) {
        const int gq = (mt & 1) * 2 + (g >> 1);
        twi[mt] = (mt >> 1) * 128 + (c16 + 16 * gq) * 2 + (g & 1);
    }

    // ================= layer 1: x^T = w1^T @ in^T =================
    f32x4 accx[4][4];
    #pragma unroll
    for (int mt = 0; mt < 4; ++mt)
        #pragma unroll
        for (int nt = 0; nt < 4; ++nt)
            accx[mt][nt] = (f32x4){0.f, 0.f, 0.f, 0.f};

    #pragma unroll
    for (int kt = 0; kt < 4; ++kt) {
        const float4* s4 = (kt < 2) ? euv4 : er4;
        const int rb = (kt & 1) * 8;
        #pragma unroll
        for (int gg = 0; gg < 4; ++gg) {                 // stage entry row chunk k=kt*32+gg*8..+7
            float4 va = s4[rb + gg * 2];
            float4 vb = s4[rb + gg * 2 + 1];
            uint4 o;
            o.x = pk2(va.x, va.y); o.y = pk2(va.z, va.w);
            o.z = pk2(vb.x, vb.y); o.w = pk2(vb.z, vb.w);
            stw[g * 64 + c16 + 16 * gg] = o;             // tile nt=g(=entry>>4)
        }
        frag_u Bf[4];
        #pragma unroll
        for (int nt = 0; nt < 4; ++nt) Bf[nt].q = stw[nt * 64 + lane];
        #pragma unroll
        for (int mt = 0; mt < 4; ++mt) {
            frag_u Af; Af.q = s_wpack[(mt * 4 + kt) * 64 + lane];
            #pragma unroll
            for (int nt = 0; nt < 4; ++nt)
                accx[mt][nt] = __builtin_amdgcn_mfma_f32_16x16x32_bf16(
                    Af.s, Bf[nt].s, accx[mt][nt], 0, 0, 0);
        }
    }

    // x = relu(x + b1) -> bf16 pairs
    unsigned xp[4][4][2];
    #pragma unroll
    for (int mt = 0; mt < 4; ++mt) {
        const f32x4 b1q = *(const f32x4*)(b1 + mt * 16 + g * 4);
        #pragma unroll
        for (int nt = 0; nt < 4; ++nt) {
            f32x4 a = relu4(accx[mt][nt] + b1q);
            xp[mt][nt][0] = pk2(a[0], a[1]);
            xp[mt][nt][1] = pk2(a[2], a[3]);
        }
    }

    unsigned ofp[4][4][2];   // o kept as bf16 packs (register saving; agg unpacks)
    float myscore = 0.f;

    // ================= layers 2-4, per entry-column tile nt =================
    #pragma unroll
    for (int nt = 0; nt < 4; ++nt) {
        // ---- x -> B' ----
        #pragma unroll
        for (int mt = 0; mt < 4; ++mt)
            t2[twi[mt]] = make_uint2(xp[mt][nt][0], xp[mt][nt][1]);
        frag_u Bp0, Bp1;
        Bp0.q = stw[lane]; Bp1.q = stw[64 + lane];

        // ---- layer 2: o = relu(w2^T @ x + b2) ----
        f32x4 acco[4];
        #pragma unroll
        for (int mt = 0; mt < 4; ++mt) acco[mt] = (f32x4){0.f, 0.f, 0.f, 0.f};
        #pragma unroll
        for (int kt2 = 0; kt2 < 2; ++kt2) {
            #pragma unroll
            for (int mt = 0; mt < 4; ++mt) {
                frag_u A; A.q = s_wpack[(16 + mt * 2 + kt2) * 64 + lane];
                acco[mt] = __builtin_amdgcn_mfma_f32_16x16x32_bf16(
                    A.s, (kt2 ? Bp1 : Bp0).s, acco[mt], 0, 0, 0);
            }
        }
        #pragma unroll
        for (int mt = 0; mt < 4; ++mt) {
            const f32x4 b2q = *(const f32x4*)(b2 + mt * 16 + g * 4);
            f32x4 o = relu4(acco[mt] + b2q);
            ofp[mt][nt][0] = pk2(o[0], o[1]);
            ofp[mt][nt][1] = pk2(o[2], o[3]);
        }

        // ---- o -> B'' ; layer 3: h1 = relu(a1^T @ o + c1) ----
        #pragma unroll
        for (int mt = 0; mt < 4; ++mt)
            t2[twi[mt]] = make_uint2(ofp[mt][nt][0], ofp[mt][nt][1]);
        Bp0.q = stw[lane]; Bp1.q = stw[64 + lane];
        f32x4 acch[4];
        #pragma unroll
        for (int mt = 0; mt < 4; ++mt) acch[mt] = (f32x4){0.f, 0.f, 0.f, 0.f};
        #pragma unroll
        for (int kt2 = 0; kt2 < 2; ++kt2) {
            #pragma unroll
            for (int mt = 0; mt < 4; ++mt) {
                frag_u A; A.q = s_wpack[(24 + mt * 2 + kt2) * 64 + lane];
                acch[mt] = __builtin_amdgcn_mfma_f32_16x16x32_bf16(
                    A.s, (kt2 ? Bp1 : Bp0).s, acch[mt], 0, 0, 0);
            }
        }
        unsigned hp0[4], hp1[4];
        #pragma unroll
        for (int mt = 0; mt < 4; ++mt) {
            const f32x4 c1q = *(const f32x4*)&s_c1[wv][mt * 16 + g * 4];
            f32x4 h = relu4(acch[mt] + c1q);
            hp0[mt] = pk2(h[0], h[1]); hp1[mt] = pk2(h[2], h[3]);
        }

        // ---- h1 -> B''' ; layer 4: h2 = relu(a2^T @ h1 + ba2); score = h2 . a3 ----
        #pragma unroll
        for (int mt = 0; mt < 4; ++mt) t2[twi[mt]] = make_uint2(hp0[mt], hp1[mt]);
        Bp0.q = stw[lane]; Bp1.q = stw[64 + lane];
        f32x4 acc2[4];
        #pragma unroll
        for (int mt = 0; mt < 4; ++mt) acc2[mt] = (f32x4){0.f, 0.f, 0.f, 0.f};
        #pragma unroll
        for (int kt2 = 0; kt2 < 2; ++kt2) {
            #pragma unroll
            for (int mt = 0; mt < 4; ++mt) {
                frag_u A; A.q = s_wpack[(32 + mt * 2 + kt2) * 64 + lane];
                acc2[mt] = __builtin_amdgcn_mfma_f32_16x16x32_bf16(
                    A.s, (kt2 ? Bp1 : Bp0).s, acc2[mt], 0, 0, 0);
            }
        }
        float s = 0.f;
        #pragma unroll
        for (int mt = 0; mt < 4; ++mt) {
            const f32x4 ba2q = *(const f32x4*)(ba2 + mt * 16 + g * 4);
            const f32x4 a3q  = *(const f32x4*)(a3  + mt * 16 + g * 4);
            #pragma unroll
            for (int r = 0; r < 4; ++r)
                s = fmaf(fmaxf(acc2[mt][r] + ba2q[r], 0.f), a3q[r], s);
        }
        s += __shfl_xor(s, 16, 64);
        s += __shfl_xor(s, 32, 64);      // score for entry nt*16+c16, replicated
        if (g == nt) myscore = s;        // lane l ends with score[l]
    }

    // ---- masked softmax over entries (lane = entry); ba3 shift-invariant, skipped ----
    const bool valid = (lane < len);
    float sv = valid ? myscore : -1e9f;
    float m = sv;
    #pragma unroll
    for (int off = 32; off >= 1; off >>= 1) m = fmaxf(m, __shfl_xor(m, off, 64));
    float e = valid ? expf(sv - m) : 0.f;
    float sum = e;
    #pragma unroll
    for (int off = 32; off >= 1; off >>= 1) sum += __shfl_xor(sum, off, 64);
    const float att = e / sum;

    // ---- agg[d] = sum_l att[l] * o[d][l]  (o in C-layout bf16 packs) ----
    float attn[4];
    #pragma unroll
    for (int nt = 0; nt < 4; ++nt) attn[nt] = __shfl(att, nt * 16 + c16, 64);

    f32x4 agg[4];
    #pragma unroll
    for (int mt = 0; mt < 4; ++mt) {
        f32x4 a = (f32x4){0.f, 0.f, 0.f, 0.f};
        #pragma unroll
        for (int nt = 0; nt < 4; ++nt) {
            a[0] = fmaf(ubf_lo(ofp[mt][nt][0]), attn[nt], a[0]);
            a[1] = fmaf(ubf_hi(ofp[mt][nt][0]), attn[nt], a[1]);
            a[2] = fmaf(ubf_lo(ofp[mt][nt][1]), attn[nt], a[2]);
            a[3] = fmaf(ubf_hi(ofp[mt][nt][1]), attn[nt], a[3]);
        }
        agg[mt] = a;
    }
    #pragma unroll
    for (int off = 1; off <= 8; off <<= 1) {
        #pragma unroll
        for (int mt = 0; mt < 4; ++mt) {
            #pragma unroll
            for (int r = 0; r < 4; ++r)
                agg[mt][r] += __shfl_xor(agg[mt][r], off, 64);
        }
    }

    if (c16 == 0) {   // 4 writer lanes x 4 mt float4 stores cover d=0..63
        #pragma unroll
        for (int mt = 0; mt < 4; ++mt) {
            f32x4 res = agg[mt];
            if (len <= 0)
                res = *(const f32x4*)(u2e + (size_t)node * 64 + mt * 16 + g * 4);
            *(f32x4*)(out + (size_t)b * 64 + mt * 16 + g * 4) = res;
        }
    }
}

extern "C" void kernel_launch(void* const* d_in, const int* in_sizes, int n_in,
                              void* d_out, int out_size, void* d_ws, size_t ws_size,
                              hipStream_t stream) {
    const int*   nodes = (const int*)d_in[0];
    const int*   huv   = (const int*)d_in[1];
    const int*   hr    = (const int*)d_in[2];
    const int*   lens  = (const int*)d_in[3];
    const float* u2e   = (const float*)d_in[4];
    const float* v2e   = (const float*)d_in[5];
    const float* r2e   = (const float*)d_in[6];
    const float* w1    = (const float*)d_in[7];
    const float* b1    = (const float*)d_in[8];
    const float* w2    = (const float*)d_in[9];
    const float* b2    = (const float*)d_in[10];
    const float* a1    = (const float*)d_in[11];
    const float* ba1   = (const float*)d_in[12];
    const float* a2    = (const float*)d_in[13];
    const float* ba2   = (const float*)d_in[14];
    const float* a3    = (const float*)d_in[15];
    const float* ba3   = (const float*)d_in[16];
    float* outp = (float*)d_out;

    uvagg<<<NB / WPB, 512, 0, stream>>>(nodes, huv, hr, lens, u2e, v2e, r2e,
                                        w1, b1, w2, b2, a1, ba1, a2, ba2, a3, ba3,
                                        outp);
}

// Round 12
// 149.514 us; speedup vs baseline: 1.1070x; 1.1070x over previous
//
#include <hip/hip_runtime.h>
#include <math.h>

#define NB 4096
#define HL 50
#define WPB 8   // waves per block; one batch row per wave; 40KB weight pack shared

typedef __attribute__((ext_vector_type(8))) short short8;   // 8 bf16 (4 VGPRs)
typedef __attribute__((ext_vector_type(4))) float f32x4;    // MFMA acc

union frag_u { uint4 q; short8 s; };

// round-to-nearest-even f32->bf16, pack two into u32 (a=low half, b=high half)
__device__ __forceinline__ unsigned pk2(float a, float b) {
    union { float f; unsigned u; } x, y;
    x.f = a; y.f = b;
    unsigned lo = (x.u + 0x7FFFu + ((x.u >> 16) & 1u)) >> 16;
    unsigned hi = (y.u + 0x7FFFu + ((y.u >> 16) & 1u)) & 0xFFFF0000u;
    return lo | hi;
}
__device__ __forceinline__ float ubf_lo(unsigned u) {
    union { unsigned v; float f; } x; x.v = u << 16; return x.f;
}
__device__ __forceinline__ float ubf_hi(unsigned u) {
    union { unsigned v; float f; } x; x.v = u & 0xFFFF0000u; return x.f;
}
__device__ __forceinline__ f32x4 relu4(f32x4 v) {
    f32x4 r;
    r[0] = fmaxf(v[0], 0.f); r[1] = fmaxf(v[1], 0.f);
    r[2] = fmaxf(v[2], 0.f); r[3] = fmaxf(v[3], 0.f);
    return r;
}

// wave = one batch row. MFMA: channels = M, entries = N.
// Weight A-fragments packed once/block (amortized over 8 waves).
// k-slot permutation applied identically on A-pack and B-stage sides -> cancels.
// launch_bounds(512,2): (512,4) squeezed VGPR to 64 -> ~100MB/dispatch scratch
// spill (R11: WRITE_SIZE 69.6MB). Cap 256 lets allocator take its natural 128.
__global__ __launch_bounds__(512, 2) void uvagg(
    const int* __restrict__ nodes,
    const int* __restrict__ history_uv,
    const int* __restrict__ history_r,
    const int* __restrict__ lengths,
    const float* __restrict__ u2e,
    const float* __restrict__ v2e,
    const float* __restrict__ r2e,
    const float* __restrict__ w1,
    const float* __restrict__ b1,
    const float* __restrict__ w2,
    const float* __restrict__ b2,
    const float* __restrict__ a1,
    const float* __restrict__ ba1,
    const float* __restrict__ a2,
    const float* __restrict__ ba2,
    const float* __restrict__ a3,
    const float* __restrict__ ba3,
    float* __restrict__ out)
{
    const int wv   = threadIdx.x >> 6;
    const int lane = threadIdx.x & 63;
    const int g    = lane >> 4;      // k-group / row-group
    const int c16  = lane & 15;      // col-within-tile
    const int b    = blockIdx.x * WPB + wv;

    __shared__ uint4 s_wpack[40 * 64];                 // 40 KB, block-shared
    __shared__ __align__(16) float s_c1[WPB][64];      // 2 KB
    __shared__ uint4 s_stage[WPB][256];                // 32 KB (B-stage / transitions)

    // ---- cooperative weight packing: tiles 0-15 w1^T, 16-23 w2^T, 24-31 a1^T(k<64), 32-39 a2^T ----
    {
        const int tid = threadIdx.x;
        #pragma unroll 1
        for (int t = tid; t < 2560; t += 512) {
            const int tile = t >> 6, ln = t & 63;
            const float* src; int kb, mt;
            if (tile < 16)      { src = w1; kb = (tile & 3) * 32; mt = tile >> 2; }
            else if (tile < 24) { src = w2; kb = (tile & 1) * 32; mt = (tile - 16) >> 1; }
            else if (tile < 32) { src = a1; kb = (tile & 1) * 32; mt = (tile - 24) >> 1; }
            else                { src = a2; kb = (tile & 1) * 32; mt = (tile - 32) >> 1; }
            const float* p = src + (size_t)(kb + (ln >> 4) * 8) * 64 + mt * 16 + (ln & 15);
            uint4 o;
            o.x = pk2(p[0 * 64], p[1 * 64]);
            o.y = pk2(p[2 * 64], p[3 * 64]);
            o.z = pk2(p[4 * 64], p[5 * 64]);
            o.w = pk2(p[6 * 64], p[7 * 64]);
            s_wpack[tile * 64 + ln] = o;
        }
    }

    const int node = nodes[b];     // uniform
    const int len  = lengths[b];   // uniform
    const float uvl = u2e[node * 64 + lane];

    // ---- c1[j] = ba1[j] + sum_k uv[k]*a1[(64+k)*64+j]  (lane = j) ----
    {
        float c1 = ba1[lane];
        #pragma unroll 16
        for (int k = 0; k < 64; ++k)
            c1 = fmaf(__shfl(uvl, k, 64), a1[(64 + k) * 64 + lane], c1);
        s_c1[wv][lane] = c1;
    }
    __syncthreads();   // weights packed + c1 ready

    // ---- gather pointers (lane = entry) ----
    const bool e_ok = (lane < HL);
    const int  hidx = b * HL + (e_ok ? lane : 0);
    const float4* euv4 = (const float4*)(v2e + (size_t)history_uv[hidx] * 64);
    const float4* er4  = (const float4*)(r2e + (size_t)history_r[hidx] * 64);

    uint4* stw = &s_stage[wv][0];
    uint2* t2  = (uint2*)stw;

    // transition write index per mt (C pair {c0,c0+1},{c0+2,c0+3} -> B' slots)
    int twi[4];
    #pragma unroll
    for (int mt = 0; mt < 4; ++mt) {
        const int gq = (mt & 1) * 2 + (g >> 1);
        twi[mt] = (mt >> 1) * 128 + (c16 + 16 * gq) * 2 + (g & 1);
    }

    // ================= layer 1: x^T = w1^T @ in^T =================
    f32x4 accx[4][4];
    #pragma unroll
    for (int mt = 0; mt < 4; ++mt)
        #pragma unroll
        for (int nt = 0; nt < 4; ++nt)
            accx[mt][nt] = (f32x4){0.f, 0.f, 0.f, 0.f};

    #pragma unroll
    for (int kt = 0; kt < 4; ++kt) {
        const float4* s4 = (kt < 2) ? euv4 : er4;
        const int rb = (kt & 1) * 8;
        #pragma unroll
        for (int gg = 0; gg < 4; ++gg) {                 // stage entry row chunk k=kt*32+gg*8..+7
            float4 va = s4[rb + gg * 2];
            float4 vb = s4[rb + gg * 2 + 1];
            uint4 o;
            o.x = pk2(va.x, va.y); o.y = pk2(va.z, va.w);
            o.z = pk2(vb.x, vb.y); o.w = pk2(vb.z, vb.w);
            stw[g * 64 + c16 + 16 * gg] = o;             // tile nt=g(=entry>>4)
        }
        frag_u Bf[4];
        #pragma unroll
        for (int nt = 0; nt < 4; ++nt) Bf[nt].q = stw[nt * 64 + lane];
        #pragma unroll
        for (int mt = 0; mt < 4; ++mt) {
            frag_u Af; Af.q = s_wpack[(mt * 4 + kt) * 64 + lane];
            #pragma unroll
            for (int nt = 0; nt < 4; ++nt)
                accx[mt][nt] = __builtin_amdgcn_mfma_f32_16x16x32_bf16(
                    Af.s, Bf[nt].s, accx[mt][nt], 0, 0, 0);
        }
    }

    // x = relu(x + b1) -> bf16 pairs
    unsigned xp[4][4][2];
    #pragma unroll
    for (int mt = 0; mt < 4; ++mt) {
        const f32x4 b1q = *(const f32x4*)(b1 + mt * 16 + g * 4);
        #pragma unroll
        for (int nt = 0; nt < 4; ++nt) {
            f32x4 a = relu4(accx[mt][nt] + b1q);
            xp[mt][nt][0] = pk2(a[0], a[1]);
            xp[mt][nt][1] = pk2(a[2], a[3]);
        }
    }

    unsigned ofp[4][4][2];   // o kept as bf16 packs (register saving; agg unpacks)
    float myscore = 0.f;

    // ================= layers 2-4, per entry-column tile nt =================
    #pragma unroll
    for (int nt = 0; nt < 4; ++nt) {
        // ---- x -> B' ----
        #pragma unroll
        for (int mt = 0; mt < 4; ++mt)
            t2[twi[mt]] = make_uint2(xp[mt][nt][0], xp[mt][nt][1]);
        frag_u Bp0, Bp1;
        Bp0.q = stw[lane]; Bp1.q = stw[64 + lane];

        // ---- layer 2: o = relu(w2^T @ x + b2) ----
        f32x4 acco[4];
        #pragma unroll
        for (int mt = 0; mt < 4; ++mt) acco[mt] = (f32x4){0.f, 0.f, 0.f, 0.f};
        #pragma unroll
        for (int kt2 = 0; kt2 < 2; ++kt2) {
            #pragma unroll
            for (int mt = 0; mt < 4; ++mt) {
                frag_u A; A.q = s_wpack[(16 + mt * 2 + kt2) * 64 + lane];
                acco[mt] = __builtin_amdgcn_mfma_f32_16x16x32_bf16(
                    A.s, (kt2 ? Bp1 : Bp0).s, acco[mt], 0, 0, 0);
            }
        }
        #pragma unroll
        for (int mt = 0; mt < 4; ++mt) {
            const f32x4 b2q = *(const f32x4*)(b2 + mt * 16 + g * 4);
            f32x4 o = relu4(acco[mt] + b2q);
            ofp[mt][nt][0] = pk2(o[0], o[1]);
            ofp[mt][nt][1] = pk2(o[2], o[3]);
        }

        // ---- o -> B'' ; layer 3: h1 = relu(a1^T @ o + c1) ----
        #pragma unroll
        for (int mt = 0; mt < 4; ++mt)
            t2[twi[mt]] = make_uint2(ofp[mt][nt][0], ofp[mt][nt][1]);
        Bp0.q = stw[lane]; Bp1.q = stw[64 + lane];
        f32x4 acch[4];
        #pragma unroll
        for (int mt = 0; mt < 4; ++mt) acch[mt] = (f32x4){0.f, 0.f, 0.f, 0.f};
        #pragma unroll
        for (int kt2 = 0; kt2 < 2; ++kt2) {
            #pragma unroll
            for (int mt = 0; mt < 4; ++mt) {
                frag_u A; A.q = s_wpack[(24 + mt * 2 + kt2) * 64 + lane];
                acch[mt] = __builtin_amdgcn_mfma_f32_16x16x32_bf16(
                    A.s, (kt2 ? Bp1 : Bp0).s, acch[mt], 0, 0, 0);
            }
        }
        unsigned hp0[4], hp1[4];
        #pragma unroll
        for (int mt = 0; mt < 4; ++mt) {
            const f32x4 c1q = *(const f32x4*)&s_c1[wv][mt * 16 + g * 4];
            f32x4 h = relu4(acch[mt] + c1q);
            hp0[mt] = pk2(h[0], h[1]); hp1[mt] = pk2(h[2], h[3]);
        }

        // ---- h1 -> B''' ; layer 4: h2 = relu(a2^T @ h1 + ba2); score = h2 . a3 ----
        #pragma unroll
        for (int mt = 0; mt < 4; ++mt) t2[twi[mt]] = make_uint2(hp0[mt], hp1[mt]);
        Bp0.q = stw[lane]; Bp1.q = stw[64 + lane];
        f32x4 acc2[4];
        #pragma unroll
        for (int mt = 0; mt < 4; ++mt) acc2[mt] = (f32x4){0.f, 0.f, 0.f, 0.f};
        #pragma unroll
        for (int kt2 = 0; kt2 < 2; ++kt2) {
            #pragma unroll
            for (int mt = 0; mt < 4; ++mt) {
                frag_u A; A.q = s_wpack[(32 + mt * 2 + kt2) * 64 + lane];
                acc2[mt] = __builtin_amdgcn_mfma_f32_16x16x32_bf16(
                    A.s, (kt2 ? Bp1 : Bp0).s, acc2[mt], 0, 0, 0);
            }
        }
        float s = 0.f;
        #pragma unroll
        for (int mt = 0; mt < 4; ++mt) {
            const f32x4 ba2q = *(const f32x4*)(ba2 + mt * 16 + g * 4);
            const f32x4 a3q  = *(const f32x4*)(a3  + mt * 16 + g * 4);
            #pragma unroll
            for (int r = 0; r < 4; ++r)
                s = fmaf(fmaxf(acc2[mt][r] + ba2q[r], 0.f), a3q[r], s);
        }
        s += __shfl_xor(s, 16, 64);
        s += __shfl_xor(s, 32, 64);      // score for entry nt*16+c16, replicated
        if (g == nt) myscore = s;        // lane l ends with score[l]
    }

    // ---- masked softmax over entries (lane = entry); ba3 shift-invariant, skipped ----
    const bool valid = (lane < len);
    float sv = valid ? myscore : -1e9f;
    float m = sv;
    #pragma unroll
    for (int off = 32; off >= 1; off >>= 1) m = fmaxf(m, __shfl_xor(m, off, 64));
    float e = valid ? expf(sv - m) : 0.f;
    float sum = e;
    #pragma unroll
    for (int off = 32; off >= 1; off >>= 1) sum += __shfl_xor(sum, off, 64);
    const float att = e / sum;

    // ---- agg[d] = sum_l att[l] * o[d][l]  (o in C-layout bf16 packs) ----
    float attn[4];
    #pragma unroll
    for (int nt = 0; nt < 4; ++nt) attn[nt] = __shfl(att, nt * 16 + c16, 64);

    f32x4 agg[4];
    #pragma unroll
    for (int mt = 0; mt < 4; ++mt) {
        f32x4 a = (f32x4){0.f, 0.f, 0.f, 0.f};
        #pragma unroll
        for (int nt = 0; nt < 4; ++nt) {
            a[0] = fmaf(ubf_lo(ofp[mt][nt][0]), attn[nt], a[0]);
            a[1] = fmaf(ubf_hi(ofp[mt][nt][0]), attn[nt], a[1]);
            a[2] = fmaf(ubf_lo(ofp[mt][nt][1]), attn[nt], a[2]);
            a[3] = fmaf(ubf_hi(ofp[mt][nt][1]), attn[nt], a[3]);
        }
        agg[mt] = a;
    }
    #pragma unroll
    for (int off = 1; off <= 8; off <<= 1) {
        #pragma unroll
        for (int mt = 0; mt < 4; ++mt) {
            #pragma unroll
            for (int r = 0; r < 4; ++r)
                agg[mt][r] += __shfl_xor(agg[mt][r], off, 64);
        }
    }

    if (c16 == 0) {   // 4 writer lanes x 4 mt float4 stores cover d=0..63
        #pragma unroll
        for (int mt = 0; mt < 4; ++mt) {
            f32x4 res = agg[mt];
            if (len <= 0)
                res = *(const f32x4*)(u2e + (size_t)node * 64 + mt * 16 + g * 4);
            *(f32x4*)(out + (size_t)b * 64 + mt * 16 + g * 4) = res;
        }
    }
}

extern "C" void kernel_launch(void* const* d_in, const int* in_sizes, int n_in,
                              void* d_out, int out_size, void* d_ws, size_t ws_size,
                              hipStream_t stream) {
    const int*   nodes = (const int*)d_in[0];
    const int*   huv   = (const int*)d_in[1];
    const int*   hr    = (const int*)d_in[2];
    const int*   lens  = (const int*)d_in[3];
    const float* u2e   = (const float*)d_in[4];
    const float* v2e   = (const float*)d_in[5];
    const float* r2e   = (const float*)d_in[6];
    const float* w1    = (const float*)d_in[7];
    const float* b1    = (const float*)d_in[8];
    const float* w2    = (const float*)d_in[9];
    const float* b2    = (const float*)d_in[10];
    const float* a1    = (const float*)d_in[11];
    const float* ba1   = (const float*)d_in[12];
    const float* a2    = (const float*)d_in[13];
    const float* ba2   = (const float*)d_in[14];
    const float* a3    = (const float*)d_in[15];
    const float* ba3   = (const float*)d_in[16];
    float* outp = (float*)d_out;

    uvagg<<<NB / WPB, 512, 0, stream>>>(nodes, huv, hr, lens, u2e, v2e, r2e,
                                        w1, b1, w2, b2, a1, ba1, a2, ba2, a3, ba3,
                                        outp);
}